// Round 1
// baseline (146.394 us; speedup 1.0000x reference)
//
#include <hip/hip_runtime.h>

#define NBINS 16384
#define LGT 128
#define LPR 128
#define NPIXF 16777216.0f  // 4096*4096; reference n_pix (fits exactly in fp32)

// ---------------- Kernel 1: per-block LDS histogram of (gt<<7)|pred ----------------
template <bool PARTIAL>
__global__ __launch_bounds__(1024) void pq_hist(const int* __restrict__ gt,
                                                const int* __restrict__ pr,
                                                unsigned* __restrict__ dst, int n) {
    __shared__ unsigned lh[NBINS];  // exactly 64 KB -> 2 blocks/CU
    for (int i = threadIdx.x; i < NBINS; i += 1024) lh[i] = 0u;
    __syncthreads();

    const int nvec = n >> 2;
    const int4* g4 = (const int4*)gt;
    const int4* p4 = (const int4*)pr;
    const int stride = gridDim.x * 1024;
    for (int i = blockIdx.x * 1024 + threadIdx.x; i < nvec; i += stride) {
        int4 g = g4[i];
        int4 p = p4[i];
        atomicAdd(&lh[(g.x << 7) | p.x], 1u);
        atomicAdd(&lh[(g.y << 7) | p.y], 1u);
        atomicAdd(&lh[(g.z << 7) | p.z], 1u);
        atomicAdd(&lh[(g.w << 7) | p.w], 1u);
    }
    // tail (n not divisible by 4) — handled by block 0 (rem < 4)
    if (blockIdx.x == 0) {
        int t = (nvec << 2) + threadIdx.x;
        if (t < n) atomicAdd(&lh[(gt[t] << 7) | pr[t]], 1u);
    }
    __syncthreads();

    if (PARTIAL) {
        unsigned* mine = dst + (size_t)blockIdx.x * NBINS;
        for (int i = threadIdx.x; i < NBINS; i += 1024) mine[i] = lh[i];
    } else {
        for (int i = threadIdx.x; i < NBINS; i += 1024) {
            unsigned v = lh[i];
            if (v) atomicAdd(&dst[i], v);
        }
    }
}

// ---------------- Kernel 2: reduce per-block partials ----------------
__global__ __launch_bounds__(256) void pq_reduce(const unsigned* __restrict__ partial,
                                                 unsigned* __restrict__ hist, int nb) {
    int bin = blockIdx.x * 256 + threadIdx.x;  // 16384 threads, one per bin
    unsigned s = 0u;
    for (int b = 0; b < nb; ++b) s += partial[(size_t)b * NBINS + bin];
    hist[bin] = s;
}

// ---------------- Kernel 3: sequential PQ matching, one wave of 64 lanes ----------------
// Lane owns pred labels p = lane (lo) and p = lane+64 (hi). Within an outer
// iteration g, all p are independent of each other (matched_pr[p] is consumed
// and produced only at (g,p); the p==0 merged sums use only state entering g),
// so a full g-iteration is one parallel wave step.
__device__ __forceinline__ float wsum64(float v) {
    for (int i = 1; i < 64; i <<= 1) v += __shfl_xor(v, i, 64);
    return v;
}

__global__ __launch_bounds__(64) void pq_match(const unsigned* __restrict__ hist,
                                               float* __restrict__ out) {
    const int lane = threadIdx.x;
    __shared__ unsigned h[NBINS];  // 64 KB
    for (int i = lane; i < NBINS; i += 64) h[i] = hist[i];
    __syncthreads();

    // area_pr for p = lane, lane+64 (column sums; consecutive lanes -> conflict-free)
    float apr_lo = 0.f, apr_hi = 0.f;
    for (int g = 0; g < LGT; ++g) {
        apr_lo += (float)h[g * LPR + lane];
        apr_hi += (float)h[g * LPR + 64 + lane];
    }
    // area_gt for rows g = lane, lane+64 (staggered column start -> 2-way max bank aliasing)
    float ag_lo = 0.f, ag_hi = 0.f;
    for (int q = 0; q < LPR; ++q) {
        int c = (q + lane) & (LPR - 1);
        ag_lo += (float)h[lane * LPR + c];
        ag_hi += (float)h[(lane + 64) * LPR + c];
    }

    const bool prp_lo = apr_lo > 0.f;
    const bool prp_hi = apr_hi > 0.f;
    bool m_lo = false, m_hi = false;  // matched_pr for my two labels
    float tp = 0.f;
    float last_iou = 0.f;
    float fn_pos = 0.f;
    bool any_pos_match = false;
    bool gt0_present = false;

    for (int g = 0; g < LGT; ++g) {
        float a_g = __shfl((g < 64) ? ag_lo : ag_hi, g & 63, 64);
        bool g_ok = a_g > 0.f;
        float r_lo = (float)h[g * LPR + lane];
        float r_hi = (float)h[g * LPR + 64 + lane];

        // merged sums over {p>=1 : matched_pr[p]} — skip when nothing matched (uniform)
        float Srow = 0.f, Sarea = 0.f;
        unsigned long long anym = __ballot(m_lo) | __ballot(m_hi);
        if (anym) {
            float mr = ((m_lo && lane != 0) ? r_lo : 0.f) + (m_hi ? r_hi : 0.f);
            float ma = ((m_lo && lane != 0) ? apr_lo : 0.f) + (m_hi ? apr_hi : 0.f);
            for (int i = 1; i < 64; i <<= 1) {
                mr += __shfl_xor(mr, i, 64);
                ma += __shfl_xor(ma, i, 64);
            }
            Srow = mr;
            Sarea = ma;
        }

        // lo slot (p = lane; lane 0 is the special p==0 case)
        float inter_lo, ap_lo;
        bool pres_lo;
        if (lane == 0) {
            inter_lo = r_lo + Srow;
            ap_lo = apr_lo + Sarea;
            pres_lo = ((NPIXF - a_g) > 0.f) || (inter_lo > 0.f);
        } else {
            inter_lo = r_lo;
            ap_lo = apr_lo;
            pres_lo = prp_lo && !m_lo && (inter_lo > 0.f);
        }
        pres_lo = pres_lo && g_ok;
        float iou_lo = inter_lo / fmaxf((a_g + ap_lo) - inter_lo, 1.f);
        bool match_lo = pres_lo && (iou_lo > 0.5f);

        // hi slot (p = lane+64, never 0)
        float inter_hi = r_hi;
        bool pres_hi = prp_hi && !m_hi && (inter_hi > 0.f) && g_ok;
        float iou_hi = inter_hi / fmaxf((a_g + apr_hi) - inter_hi, 1.f);
        bool match_hi = pres_hi && (iou_hi > 0.5f);

        // state updates
        m_lo = m_lo || (match_lo && lane != 0);
        m_hi = m_hi || match_hi;

        unsigned long long bml = __ballot(match_lo), bmh = __ballot(match_hi);
        tp += (float)(__popcll(bml) + __popcll(bmh));
        bool match_any = (bml | bmh) != 0ull;
        if (g == 0) {
            gt0_present = g_ok;
        } else {
            any_pos_match = any_pos_match || match_any;
            if (g_ok && !match_any) fn_pos += 1.f;
        }

        // last present pair in sequential order -> highest present p this g
        unsigned long long bpl = __ballot(pres_lo), bph = __ballot(pres_hi);
        int src;
        bool usehi;
        if (bph) {
            src = 63 - __clzll(bph);
            usehi = true;
        } else if (bpl) {
            src = 63 - __clzll(bpl);
            usehi = false;
        } else {
            src = 0;
            usehi = false;
        }
        float cand_hi = __shfl(iou_hi, src, 64);
        float cand_lo = __shfl(iou_lo, src, 64);
        if ((bph | bpl) != 0ull) last_iou = usehi ? cand_hi : cand_lo;
    }

    // fp = zero_pr + #{p>=1 : pr_present & !matched_pr}
    float fpv = ((lane != 0 && prp_lo && !m_lo) ? 1.f : 0.f) + ((prp_hi && !m_hi) ? 1.f : 0.f);
    fpv = wsum64(fpv);
    unsigned long long bml_f = __ballot(m_lo && lane != 0);
    unsigned long long bmh_f = __ballot(m_hi);
    bool pr0_present = (__ballot(prp_lo) & 1ull) != 0ull;
    bool zero_pr = pr0_present || (bml_f != 0ull) || (bmh_f != 0ull);
    bool zero_gt = gt0_present || any_pos_match;

    float fn = (zero_gt ? 1.f : 0.f) + fn_pos;
    float fp = (zero_pr ? 1.f : 0.f) + fpv;
    float res = last_iou / (tp + 0.5f * (fn + fp));
    if (lane == 0) out[0] = res;
}

// ---------------- launch ----------------
extern "C" void kernel_launch(void* const* d_in, const int* in_sizes, int n_in,
                              void* d_out, int out_size, void* d_ws, size_t ws_size,
                              hipStream_t stream) {
    const int* gt = (const int*)d_in[0];
    const int* pr = (const int*)d_in[1];
    const int n = in_sizes[0];

    unsigned* hist = (unsigned*)d_ws;           // [NBINS]
    unsigned* partial = hist + NBINS;           // [NB][NBINS]
    const int NB = 512;
    const size_t needA = (size_t)(NB + 1) * NBINS * sizeof(unsigned);

    if (ws_size >= needA) {
        pq_hist<true><<<NB, 1024, 0, stream>>>(gt, pr, partial, n);
        pq_reduce<<<NBINS / 256, 256, 0, stream>>>(partial, hist, NB);
    } else {
        hipMemsetAsync(d_ws, 0, NBINS * sizeof(unsigned), stream);
        pq_hist<false><<<NB, 1024, 0, stream>>>(gt, pr, hist, n);
    }
    pq_match<<<1, 64, 0, stream>>>(hist, (float*)d_out);
}

// Round 2
// 85.199 us; speedup vs baseline: 1.7183x; 1.7183x over previous
//
#include <hip/hip_runtime.h>

#define NBINS 16384
#define LGT 128
#define LPR 128
#define NPIXF 16777216.0f  // 4096*4096; reference n_pix (fits exactly in fp32)
#define NB 512             // histogram blocks
#define CH 32              // partials summed per reduce-thread (512/32 = 16 chunks)

// ---------------- Kernel 1: per-block LDS histogram of (gt<<7)|pred ----------------
// Grid-stride geometry gives exactly 32768 pixels/block -> per-block bin count
// <= 32768 < 65536, so partials fit ushort (halves flush+reduce traffic).
template <bool PARTIAL>
__global__ __launch_bounds__(1024) void pq_hist(const int* __restrict__ gt,
                                                const int* __restrict__ pr,
                                                unsigned short* __restrict__ dstp,
                                                unsigned* __restrict__ dsta, int n) {
    __shared__ unsigned lh[NBINS];  // exactly 64 KB -> 2 blocks/CU
    for (int i = threadIdx.x; i < NBINS; i += 1024) lh[i] = 0u;
    __syncthreads();

    const int nvec = n >> 2;
    const int4* g4 = (const int4*)gt;
    const int4* p4 = (const int4*)pr;
    const int stride = gridDim.x * 1024;
    for (int i = blockIdx.x * 1024 + threadIdx.x; i < nvec; i += stride) {
        int4 g = g4[i];
        int4 p = p4[i];
        atomicAdd(&lh[(g.x << 7) | p.x], 1u);
        atomicAdd(&lh[(g.y << 7) | p.y], 1u);
        atomicAdd(&lh[(g.z << 7) | p.z], 1u);
        atomicAdd(&lh[(g.w << 7) | p.w], 1u);
    }
    // tail (n not divisible by 4) — handled by block 0 (rem < 4)
    if (blockIdx.x == 0) {
        int t = (nvec << 2) + threadIdx.x;
        if (t < n) atomicAdd(&lh[(gt[t] << 7) | pr[t]], 1u);
    }
    __syncthreads();

    if (PARTIAL) {
        unsigned short* mine = dstp + (size_t)blockIdx.x * NBINS;
        for (int i = threadIdx.x; i < NBINS; i += 1024) mine[i] = (unsigned short)lh[i];
    } else {
        for (int i = threadIdx.x; i < NBINS; i += 1024) {
            unsigned v = lh[i];
            if (v) atomicAdd(&dsta[i], v);
        }
    }
}

// ---------------- Kernel 2: reduce per-block ushort partials ----------------
// 262144 threads: thread (chunk, bin) sums CH=32 partials for its bin, one
// atomicAdd per thread (16 adds/bin total). Lane-consecutive bins -> coalesced.
__global__ __launch_bounds__(256) void pq_reduce(const unsigned short* __restrict__ partial,
                                                 unsigned* __restrict__ hist) {
    int idx = blockIdx.x * 256 + threadIdx.x;  // 0 .. NBINS*(NB/CH) - 1
    int bin = idx & (NBINS - 1);
    int chunk = idx >> 14;
    const unsigned short* p = partial + (size_t)chunk * CH * NBINS + bin;
    unsigned s = 0u;
#pragma unroll
    for (int k = 0; k < CH; ++k) s += (unsigned)p[(size_t)k * NBINS];
    atomicAdd(&hist[bin], s);
}

// ---------------- Kernel 3: sequential PQ matching, one wave of 64 lanes ----------------
// Lane owns pred labels p = lane (lo) and p = lane+64 (hi). Within an outer
// iteration g, all p are independent (matched_pr[p] consumed/produced only at
// (g,p); the p==0 merged sums use only state entering g), so one g-iteration
// is one parallel wave step.
__device__ __forceinline__ float wsum64(float v) {
    for (int i = 1; i < 64; i <<= 1) v += __shfl_xor(v, i, 64);
    return v;
}

__global__ __launch_bounds__(64) void pq_match(const unsigned* __restrict__ hist,
                                               float* __restrict__ out) {
    const int lane = threadIdx.x;
    __shared__ unsigned h[NBINS];  // 64 KB
    for (int i = lane; i < NBINS; i += 64) h[i] = hist[i];
    __syncthreads();

    // area_pr for p = lane, lane+64 (column sums; consecutive lanes -> conflict-free)
    float apr_lo = 0.f, apr_hi = 0.f;
    for (int g = 0; g < LGT; ++g) {
        apr_lo += (float)h[g * LPR + lane];
        apr_hi += (float)h[g * LPR + 64 + lane];
    }
    // area_gt for rows g = lane, lane+64 (staggered column start -> bounded aliasing)
    float ag_lo = 0.f, ag_hi = 0.f;
    for (int q = 0; q < LPR; ++q) {
        int c = (q + lane) & (LPR - 1);
        ag_lo += (float)h[lane * LPR + c];
        ag_hi += (float)h[(lane + 64) * LPR + c];
    }

    const bool prp_lo = apr_lo > 0.f;
    const bool prp_hi = apr_hi > 0.f;
    bool m_lo = false, m_hi = false;  // matched_pr for my two labels
    float tp = 0.f;
    float last_iou = 0.f;
    float fn_pos = 0.f;
    bool any_pos_match = false;
    bool gt0_present = false;

    for (int g = 0; g < LGT; ++g) {
        float a_g = __shfl((g < 64) ? ag_lo : ag_hi, g & 63, 64);
        bool g_ok = a_g > 0.f;
        float r_lo = (float)h[g * LPR + lane];
        float r_hi = (float)h[g * LPR + 64 + lane];

        // merged sums over {p>=1 : matched_pr[p]} — skip when nothing matched (uniform)
        float Srow = 0.f, Sarea = 0.f;
        unsigned long long anym = __ballot(m_lo && lane != 0) | __ballot(m_hi);
        if (anym) {
            float mr = ((m_lo && lane != 0) ? r_lo : 0.f) + (m_hi ? r_hi : 0.f);
            float ma = ((m_lo && lane != 0) ? apr_lo : 0.f) + (m_hi ? apr_hi : 0.f);
            for (int i = 1; i < 64; i <<= 1) {
                mr += __shfl_xor(mr, i, 64);
                ma += __shfl_xor(ma, i, 64);
            }
            Srow = mr;
            Sarea = ma;
        }

        // lo slot (p = lane; lane 0 is the special p==0 case)
        float inter_lo, ap_lo;
        bool pres_lo;
        if (lane == 0) {
            inter_lo = r_lo + Srow;
            ap_lo = apr_lo + Sarea;
            pres_lo = ((NPIXF - a_g) > 0.f) || (inter_lo > 0.f);
        } else {
            inter_lo = r_lo;
            ap_lo = apr_lo;
            pres_lo = prp_lo && !m_lo && (inter_lo > 0.f);
        }
        pres_lo = pres_lo && g_ok;
        float iou_lo = inter_lo / fmaxf((a_g + ap_lo) - inter_lo, 1.f);
        bool match_lo = pres_lo && (iou_lo > 0.5f);

        // hi slot (p = lane+64, never 0)
        float inter_hi = r_hi;
        bool pres_hi = prp_hi && !m_hi && (inter_hi > 0.f) && g_ok;
        float iou_hi = inter_hi / fmaxf((a_g + apr_hi) - inter_hi, 1.f);
        bool match_hi = pres_hi && (iou_hi > 0.5f);

        // state updates
        m_lo = m_lo || (match_lo && lane != 0);
        m_hi = m_hi || match_hi;

        unsigned long long bml = __ballot(match_lo), bmh = __ballot(match_hi);
        tp += (float)(__popcll(bml) + __popcll(bmh));
        bool match_any = (bml | bmh) != 0ull;
        if (g == 0) {
            gt0_present = g_ok;
        } else {
            any_pos_match = any_pos_match || match_any;
            if (g_ok && !match_any) fn_pos += 1.f;
        }

        // last present pair in sequential order -> highest present p this g.
        // usehi/src are wave-uniform, so select locally then ONE shuffle.
        unsigned long long bpl = __ballot(pres_lo), bph = __ballot(pres_hi);
        bool usehi = bph != 0ull;
        int src = usehi ? (63 - __clzll(bph)) : (bpl ? (63 - __clzll(bpl)) : 0);
        float val = usehi ? iou_hi : iou_lo;
        float cand = __shfl(val, src, 64);
        if ((bph | bpl) != 0ull) last_iou = cand;
    }

    // fp = zero_pr + #{p>=1 : pr_present & !matched_pr}
    float fpv = ((lane != 0 && prp_lo && !m_lo) ? 1.f : 0.f) + ((prp_hi && !m_hi) ? 1.f : 0.f);
    fpv = wsum64(fpv);
    unsigned long long bml_f = __ballot(m_lo && lane != 0);
    unsigned long long bmh_f = __ballot(m_hi);
    bool pr0_present = (__ballot(prp_lo) & 1ull) != 0ull;
    bool zero_pr = pr0_present || (bml_f != 0ull) || (bmh_f != 0ull);
    bool zero_gt = gt0_present || any_pos_match;

    float fn = (zero_gt ? 1.f : 0.f) + fn_pos;
    float fp = (zero_pr ? 1.f : 0.f) + fpv;
    float res = last_iou / (tp + 0.5f * (fn + fp));
    if (lane == 0) out[0] = res;
}

// ---------------- launch ----------------
extern "C" void kernel_launch(void* const* d_in, const int* in_sizes, int n_in,
                              void* d_out, int out_size, void* d_ws, size_t ws_size,
                              hipStream_t stream) {
    const int* gt = (const int*)d_in[0];
    const int* pr = (const int*)d_in[1];
    const int n = in_sizes[0];

    unsigned* hist = (unsigned*)d_ws;                       // [NBINS] u32
    unsigned short* partial = (unsigned short*)(hist + NBINS);  // [NB][NBINS] u16
    const size_t needA = (size_t)NBINS * sizeof(unsigned) +
                         (size_t)NB * NBINS * sizeof(unsigned short);

    hipMemsetAsync(hist, 0, NBINS * sizeof(unsigned), stream);
    if (ws_size >= needA) {
        pq_hist<true><<<NB, 1024, 0, stream>>>(gt, pr, partial, hist, n);
        pq_reduce<<<(NBINS * (NB / CH)) / 256, 256, 0, stream>>>(partial, hist);
    } else {
        pq_hist<false><<<NB, 1024, 0, stream>>>(gt, pr, partial, hist, n);
    }
    pq_match<<<1, 64, 0, stream>>>(hist, (float*)d_out);
}

// Round 3
// 45.213 us; speedup vs baseline: 3.2379x; 1.8844x over previous
//
#include <hip/hip_runtime.h>

#define NBINS 16384
#define LGT 128
#define LPR 128
#define NB 512             // histogram blocks
#define CH 32              // partials summed per reduce-thread (512/32 = 16 chunks)

// ---------------- Kernel 1: per-block LDS histogram of (gt<<7)|pred ----------------
// Grid-stride geometry gives exactly 32768 pixels/block -> per-block bin count
// <= 32768 < 65536, so partials fit ushort (halves flush+reduce traffic).
template <bool PARTIAL>
__global__ __launch_bounds__(1024) void pq_hist(const int* __restrict__ gt,
                                                const int* __restrict__ pr,
                                                unsigned short* __restrict__ dstp,
                                                unsigned* __restrict__ dsta, int n) {
    __shared__ unsigned lh[NBINS];  // exactly 64 KB -> 2 blocks/CU
    for (int i = threadIdx.x; i < NBINS; i += 1024) lh[i] = 0u;
    __syncthreads();

    const int nvec = n >> 2;
    const int4* g4 = (const int4*)gt;
    const int4* p4 = (const int4*)pr;
    const int stride = gridDim.x * 1024;
    for (int i = blockIdx.x * 1024 + threadIdx.x; i < nvec; i += stride) {
        int4 g = g4[i];
        int4 p = p4[i];
        atomicAdd(&lh[(g.x << 7) | p.x], 1u);
        atomicAdd(&lh[(g.y << 7) | p.y], 1u);
        atomicAdd(&lh[(g.z << 7) | p.z], 1u);
        atomicAdd(&lh[(g.w << 7) | p.w], 1u);
    }
    if (blockIdx.x == 0) {  // tail (n % 4 < 4)
        int t = (nvec << 2) + threadIdx.x;
        if (t < n) atomicAdd(&lh[(gt[t] << 7) | pr[t]], 1u);
    }
    __syncthreads();

    if (PARTIAL) {
        unsigned short* mine = dstp + (size_t)blockIdx.x * NBINS;
        for (int i = threadIdx.x; i < NBINS; i += 1024) mine[i] = (unsigned short)lh[i];
    } else {
        for (int i = threadIdx.x; i < NBINS; i += 1024) {
            unsigned v = lh[i];
            if (v) atomicAdd(&dsta[i], v);
        }
    }
}

// ---------------- Kernel 2: reduce per-block ushort partials ----------------
__global__ __launch_bounds__(256) void pq_reduce(const unsigned short* __restrict__ partial,
                                                 unsigned* __restrict__ hist) {
    int idx = blockIdx.x * 256 + threadIdx.x;  // 0 .. NBINS*(NB/CH) - 1
    int bin = idx & (NBINS - 1);
    int chunk = idx >> 14;
    const unsigned short* p = partial + (size_t)chunk * CH * NBINS + bin;
    unsigned s = 0u;
#pragma unroll
    for (int k = 0; k < CH; ++k) s += (unsigned)p[(size_t)k * NBINS];
    atomicAdd(&hist[bin], s);
}

// ---------------- Kernel 3: parallel phase-A evaluation + (rare) sequential fallback -------
// Inductive fact: the FIRST match in the reference's (g outer, p inner) scan
// occurs with empty matched/merged state, so it is also a match under the
// empty-state evaluation of all (g,p) pairs. If phase A (all pairs, empty
// state, 1024 threads) finds NO match, the sequential process never mutates
// state and everything has a closed form. Otherwise wave 0 runs the exact
// sequential emulation (verified in rounds 1-2).
__global__ __launch_bounds__(1024) void pq_match2(const unsigned* __restrict__ hist,
                                                  float* __restrict__ out, int n) {
    __shared__ unsigned h[NBINS];   // 64 KB
    __shared__ float agf[LGT];
    __shared__ float aprf[LPR];
    __shared__ int wkey[16];
    __shared__ float wiou[16];
    __shared__ unsigned wmatch[16];

    const int tid = threadIdx.x;
    const int lane = tid & 63;
    const int wv = tid >> 6;
    const float npix = (float)n;

    for (int i = tid; i < NBINS; i += 1024) h[i] = hist[i];
    __syncthreads();

    // areas: 8 threads per row (and per column); integer sums <= 2^24 are exact
    // in fp32 regardless of order, so any reduction order matches the reference.
    {
        int r = tid >> 3, s = (tid & 7) * 16;
        float a = 0.f;
        for (int k = 0; k < 16; ++k) a += (float)h[r * LPR + s + k];
        for (int i = 1; i < 8; i <<= 1) a += __shfl_xor(a, i, 64);
        float b = 0.f;
        for (int k = 0; k < 16; ++k) b += (float)h[(s + k) * LPR + r];
        for (int i = 1; i < 8; i <<= 1) b += __shfl_xor(b, i, 64);
        if ((tid & 7) == 0) { agf[r] = a; aprf[r] = b; }
    }
    __syncthreads();

    // phase A: empty-state evaluation of all 16384 pairs, 16 per thread
    int lkey = 0;       // (g*128+p)+1 of the last (max-index) present pair seen
    float liou = 0.f;   // its iou
    bool lmatch = false;
    for (int k = 0; k < 16; ++k) {
        int idx = tid + (k << 10);           // ascending -> overwrite keeps max
        int g = idx >> 7, p = idx & 127;
        float inter = (float)h[idx];
        float a_g = agf[g], a_p = aprf[p];
        bool present;
        if (p == 0) present = ((npix - a_g) > 0.f) || (inter > 0.f);
        else        present = (a_p > 0.f) && (inter > 0.f);
        present = present && (a_g > 0.f);
        float iou = inter / fmaxf((a_g + a_p) - inter, 1.f);
        if (present) { lkey = idx + 1; liou = iou; lmatch = lmatch || (iou > 0.5f); }
    }
    unsigned long long mb = __ballot(lmatch);
    for (int i = 1; i < 64; i <<= 1) {
        int ok = __shfl_xor(lkey, i, 64);
        float oi = __shfl_xor(liou, i, 64);
        if (ok > lkey) { lkey = ok; liou = oi; }
    }
    if (lane == 0) { wkey[wv] = lkey; wiou[wv] = liou; wmatch[wv] = (mb != 0ull) ? 1u : 0u; }
    __syncthreads();

    if (wv != 0) return;

    // wave 0: combine the 16 wave results
    int key = (lane < 16) ? wkey[lane] : 0;
    float io = (lane < 16) ? wiou[lane] : 0.f;
    unsigned am = (lane < 16) ? wmatch[lane] : 0u;
    bool anym = __ballot(am != 0u) != 0ull;
    for (int i = 1; i < 16; i <<= 1) {
        int ok = __shfl_xor(key, i, 64);
        float oi = __shfl_xor(io, i, 64);
        if (ok > key) { key = ok; io = oi; }
    }

    if (!anym) {
        // closed form: tp=0, matched sets empty
        bool gok_lo = (lane != 0) && (agf[lane] > 0.f);
        bool gok_hi = agf[lane + 64] > 0.f;
        float fn_pos = (float)(__popcll(__ballot(gok_lo)) + __popcll(__ballot(gok_hi)));
        bool pok_lo = (lane != 0) && (aprf[lane] > 0.f);
        bool pok_hi = aprf[lane + 64] > 0.f;
        float fpv = (float)(__popcll(__ballot(pok_lo)) + __popcll(__ballot(pok_hi)));
        float fn = ((agf[0] > 0.f) ? 1.f : 0.f) + fn_pos;
        float fp = ((aprf[0] > 0.f) ? 1.f : 0.f) + fpv;
        float last_iou = (key > 0) ? io : 0.f;
        if (lane == 0) out[0] = last_iou / (0.5f * (fn + fp));
        return;
    }

    // ---------- sequential fallback (exact emulation; verified in R1/R2) ----------
    float apr_lo = aprf[lane], apr_hi = aprf[lane + 64];
    const bool prp_lo = apr_lo > 0.f;
    const bool prp_hi = apr_hi > 0.f;
    bool m_lo = false, m_hi = false;
    float tp = 0.f, last_iou = 0.f, fn_pos = 0.f;
    bool any_pos_match = false, gt0_present = false;

    for (int g = 0; g < LGT; ++g) {
        float a_g = agf[g];
        bool g_ok = a_g > 0.f;
        float r_lo = (float)h[g * LPR + lane];
        float r_hi = (float)h[g * LPR + 64 + lane];

        float Srow = 0.f, Sarea = 0.f;
        unsigned long long anymb = __ballot(m_lo && lane != 0) | __ballot(m_hi);
        if (anymb) {
            float mr = ((m_lo && lane != 0) ? r_lo : 0.f) + (m_hi ? r_hi : 0.f);
            float ma = ((m_lo && lane != 0) ? apr_lo : 0.f) + (m_hi ? apr_hi : 0.f);
            for (int i = 1; i < 64; i <<= 1) {
                mr += __shfl_xor(mr, i, 64);
                ma += __shfl_xor(ma, i, 64);
            }
            Srow = mr;
            Sarea = ma;
        }

        float inter_lo, ap_lo;
        bool pres_lo;
        if (lane == 0) {
            inter_lo = r_lo + Srow;
            ap_lo = apr_lo + Sarea;
            pres_lo = ((npix - a_g) > 0.f) || (inter_lo > 0.f);
        } else {
            inter_lo = r_lo;
            ap_lo = apr_lo;
            pres_lo = prp_lo && !m_lo && (inter_lo > 0.f);
        }
        pres_lo = pres_lo && g_ok;
        float iou_lo = inter_lo / fmaxf((a_g + ap_lo) - inter_lo, 1.f);
        bool match_lo = pres_lo && (iou_lo > 0.5f);

        float inter_hi = r_hi;
        bool pres_hi = prp_hi && !m_hi && (inter_hi > 0.f) && g_ok;
        float iou_hi = inter_hi / fmaxf((a_g + apr_hi) - inter_hi, 1.f);
        bool match_hi = pres_hi && (iou_hi > 0.5f);

        m_lo = m_lo || (match_lo && lane != 0);
        m_hi = m_hi || match_hi;

        unsigned long long bml = __ballot(match_lo), bmh = __ballot(match_hi);
        tp += (float)(__popcll(bml) + __popcll(bmh));
        bool match_any = (bml | bmh) != 0ull;
        if (g == 0) {
            gt0_present = g_ok;
        } else {
            any_pos_match = any_pos_match || match_any;
            if (g_ok && !match_any) fn_pos += 1.f;
        }

        unsigned long long bpl = __ballot(pres_lo), bph = __ballot(pres_hi);
        bool usehi = bph != 0ull;
        int src = usehi ? (63 - __clzll(bph)) : (bpl ? (63 - __clzll(bpl)) : 0);
        float val = usehi ? iou_hi : iou_lo;
        float cand = __shfl(val, src, 64);
        if ((bph | bpl) != 0ull) last_iou = cand;
    }

    float fpv = ((lane != 0 && prp_lo && !m_lo) ? 1.f : 0.f) + ((prp_hi && !m_hi) ? 1.f : 0.f);
    for (int i = 1; i < 64; i <<= 1) fpv += __shfl_xor(fpv, i, 64);
    bool zero_pr = ((__ballot(prp_lo) & 1ull) != 0ull) ||
                   (__ballot(m_lo && lane != 0) != 0ull) || (__ballot(m_hi) != 0ull);
    bool zero_gt = gt0_present || any_pos_match;

    float fn = (zero_gt ? 1.f : 0.f) + fn_pos;
    float fp = (zero_pr ? 1.f : 0.f) + fpv;
    if (lane == 0) out[0] = last_iou / (tp + 0.5f * (fn + fp));
}

// ---------------- launch ----------------
extern "C" void kernel_launch(void* const* d_in, const int* in_sizes, int n_in,
                              void* d_out, int out_size, void* d_ws, size_t ws_size,
                              hipStream_t stream) {
    const int* gt = (const int*)d_in[0];
    const int* pr = (const int*)d_in[1];
    const int n = in_sizes[0];

    unsigned* hist = (unsigned*)d_ws;                           // [NBINS] u32
    unsigned short* partial = (unsigned short*)(hist + NBINS);  // [NB][NBINS] u16
    const size_t needA = (size_t)NBINS * sizeof(unsigned) +
                         (size_t)NB * NBINS * sizeof(unsigned short);

    hipMemsetAsync(hist, 0, NBINS * sizeof(unsigned), stream);
    if (ws_size >= needA) {
        pq_hist<true><<<NB, 1024, 0, stream>>>(gt, pr, partial, hist, n);
        pq_reduce<<<(NBINS * (NB / CH)) / 256, 256, 0, stream>>>(partial, hist);
    } else {
        pq_hist<false><<<NB, 1024, 0, stream>>>(gt, pr, partial, hist, n);
    }
    pq_match2<<<1, 1024, 0, stream>>>(hist, (float*)d_out, n);
}